// Round 5
// baseline (275.244 us; speedup 1.0000x reference)
//
#include <hip/hip_runtime.h>
#include <stdint.h>

// ---------------------------------------------------------------------------
// WideAndDeep: B=16384, F=3, C=256, D=64, H=1024, ND=13
// deep_in = 205 padded to 256.
// GEMM: barrier-free direct-to-register MFMA. Each wave owns a 64x64 output
// tile, loads its own A/B fragments global->VGPR (the 16x16x32 A-frag layout
// IS a row-major dwordx4 load), 2-stage software pipeline, NO LDS, NO
// __syncthreads in the K-loop. Cross-wave reuse via L1/L2 (XCD swizzle keeps
// an A-band's 8 sharer blocks on one XCD's L2).
// ---------------------------------------------------------------------------

#define BATCH 16384
#define HDIM 1024
#define KPAD 256
#define DEEP_IN 205

typedef short bf16x8 __attribute__((ext_vector_type(8)));
typedef float f32x4 __attribute__((ext_vector_type(4)));
typedef uint16_t u16x8 __attribute__((ext_vector_type(8)));

__device__ __forceinline__ float bf2f(uint16_t u) {
    uint32_t x = ((uint32_t)u) << 16;
    float f;
    __builtin_memcpy(&f, &x, 4);
    return f;
}

__device__ __forceinline__ uint16_t f2bf(float f) {
    uint32_t x;
    __builtin_memcpy(&x, &f, 4);
    uint32_t r = (x + 0x7fffu + ((x >> 16) & 1u)) >> 16;
    return (uint16_t)r;
}

// ---------------------------------------------------------------------------
// Fused prep:
//   blocks [0, 2048)      : build deep_x  [B][256] bf16  (x8 vectorized)
//   blocks [2048, 2560)   : W2 -> bf16               (x8 vectorized)
//   blocks [2560, 2688)   : W1 -> bf16 K-padded      (x8 vectorized)
//   blocks [2688, 2752)   : wide path (fp32 gathers)
// ---------------------------------------------------------------------------
__global__ __launch_bounds__(256) void prep_kernel(
    const int* __restrict__ sp, const float* __restrict__ dense,
    const float* __restrict__ emb,
    const float* __restrict__ W1, const float* __restrict__ W2,
    const float* __restrict__ ww, const float* __restrict__ wb,
    uint16_t* __restrict__ dx, uint16_t* __restrict__ W1b,
    uint16_t* __restrict__ W2b, float* __restrict__ wide)
{
    const int bid = blockIdx.x;
    if (bid < 2048) {                      // ---- deep_x build
        int idx = bid * 256 + threadIdx.x; // < 16384*32
        int b = idx >> 5, c0 = (idx & 31) * 8;
        u16x8 o;
        if (c0 < 192) {
            int f = c0 >> 6, cc = c0 & 63;
            int s = sp[b * 3 + f];
            const float* e = emb + (size_t)(((f << 8) + s) * 64 + cc);
            float4 v0 = *(const float4*)e;
            float4 v1 = *(const float4*)(e + 4);
            o[0] = f2bf(v0.x); o[1] = f2bf(v0.y); o[2] = f2bf(v0.z); o[3] = f2bf(v0.w);
            o[4] = f2bf(v1.x); o[5] = f2bf(v1.y); o[6] = f2bf(v1.z); o[7] = f2bf(v1.w);
        } else {
#pragma unroll
            for (int t = 0; t < 8; t++) {
                int c = c0 + t;
                o[t] = (c >= 192 && c < DEEP_IN) ? f2bf(dense[b * 13 + (c - 192)])
                                                 : (uint16_t)0;
            }
        }
        *(u16x8*)(dx + (size_t)idx * 8) = o;
    } else if (bid < 2560) {               // ---- W2 convert
        int k = (bid - 2048) * 256 + threadIdx.x;  // < 131072
        const float* src = W2 + (size_t)k * 8;
        float4 v0 = *(const float4*)src;
        float4 v1 = *(const float4*)(src + 4);
        u16x8 o;
        o[0] = f2bf(v0.x); o[1] = f2bf(v0.y); o[2] = f2bf(v0.z); o[3] = f2bf(v0.w);
        o[4] = f2bf(v1.x); o[5] = f2bf(v1.y); o[6] = f2bf(v1.z); o[7] = f2bf(v1.w);
        *(u16x8*)(W2b + (size_t)k * 8) = o;
    } else if (bid < 2688) {               // ---- W1 convert, pad 205->256
        int idx = (bid - 2560) * 256 + threadIdx.x;  // < 32768
        int n = idx >> 5, c0 = (idx & 31) * 8;
        u16x8 o;
#pragma unroll
        for (int t = 0; t < 8; t++) {
            int c = c0 + t;
            o[t] = (c < DEEP_IN) ? f2bf(W1[n * DEEP_IN + c]) : (uint16_t)0;
        }
        *(u16x8*)(W1b + (size_t)idx * 8) = o;
    } else {                               // ---- wide path
        int b = (bid - 2688) * 256 + threadIdx.x;  // < 16384
        int s0 = sp[b * 3], s1 = sp[b * 3 + 1], s2 = sp[b * 3 + 2];
        float w = wb[0];
        w += ww[s0] + ww[256 + s1] + ww[512 + s2];
        w += ww[768    + s0 * 3 + s1];
        w += ww[66304  + s0 * 3 + s2];
        w += ww[131840 + s1 * 3 + s2];
        w += ww[197376 + (s0 * 3 + s1) * 3 + s2];
        const float* wd = ww + 16974592;
        float acc = 0.f;
#pragma unroll
        for (int j = 0; j < 13; j++) acc += dense[b * 13 + j] * wd[j];
        wide[b] = w + acc;
    }
}

// ---------------------------------------------------------------------------
// bf16 GEMM: C[M][N] = act(A[M][K] @ Bw[N][K]^T + bias[N])  (all row-major)
// 256 threads = 4 waves, each computing 64x64 (wm = wave>>1, wn = wave&1).
// Fragment i of A: lane l reads A[(tile_m + i*16 + (l&15))*K + k0 + (l>>4)*8]
// — one global_load_dwordx4 per lane, no LDS, no barriers.
// 2-stage pipeline: frags for k+32 and k+64 in flight while computing k.
// Requires M%128==0, N==1024 (swizzle hardcodes nx=8), K%64==0, 16B-aligned.
// 1D grid (M/128)*8; XCD swizzle keeps one m-band's 8 n-blocks on one XCD.
// ---------------------------------------------------------------------------
__global__ __launch_bounds__(256) void gemm_bt(
    const uint16_t* __restrict__ A, const uint16_t* __restrict__ Bw,
    const float* __restrict__ bias, uint16_t* __restrict__ C,
    int M, int N, int K, int relu)
{
    const int tid = threadIdx.x;
    const int lane = tid & 63;
    const int wave = tid >> 6;   // 0..3
    const int wm = wave >> 1;    // 0..1 : m-half (64 rows)
    const int wn = wave & 1;     // 0..1 : n-half (64 cols)

    const int id = blockIdx.x;
    const int xcd = id & 7;
    const int slot = id >> 3;
    const int mb8 = (M >> 7) >> 3;
    const int by = xcd * mb8 + (slot >> 3);
    const int bx = slot & 7;
    const int bm = by * 128;
    const int bn = bx * 128;
    const int rl = lane & 15, q = lane >> 4;

    // Per-lane fragment base pointers; frag i at +i*16 rows.
    const uint16_t* aP = A + (size_t)(bm + wm * 64 + rl) * K + q * 8;
    const uint16_t* bP = Bw + (size_t)(bn + wn * 64 + rl) * K + q * 8;
    const size_t rs16 = (size_t)16 * K;  // 16-row stride

    f32x4 acc[4][4];
#pragma unroll
    for (int i = 0; i < 4; i++)
#pragma unroll
        for (int j = 0; j < 4; j++) acc[i][j] = (f32x4)0.f;

    bf16x8 a0[4], b0[4], a1[4], b1[4];

#define LOADF(AR, BR, KO)                                                     \
    _Pragma("unroll") for (int i = 0; i < 4; i++)                             \
        AR[i] = *(const bf16x8*)(aP + (size_t)i * rs16 + (KO));               \
    _Pragma("unroll") for (int j = 0; j < 4; j++)                             \
        BR[j] = *(const bf16x8*)(bP + (size_t)j * rs16 + (KO));

#define MFMA16(AR, BR)                                                        \
    _Pragma("unroll") for (int i = 0; i < 4; i++)                             \
        _Pragma("unroll") for (int j = 0; j < 4; j++)                         \
            acc[i][j] = __builtin_amdgcn_mfma_f32_16x16x32_bf16(              \
                AR[i], BR[j], acc[i][j], 0, 0, 0);

    LOADF(a0, b0, 0)
    LOADF(a1, b1, 32)
    for (int k0 = 64; k0 < K; k0 += 64) {
        MFMA16(a0, b0)
        LOADF(a0, b0, k0)
        MFMA16(a1, b1)
        LOADF(a1, b1, k0 + 32)
    }
    MFMA16(a0, b0)
    MFMA16(a1, b1)

#undef LOADF
#undef MFMA16

    // Epilogue: C/D layout col = lane&15, row = (lane>>4)*4 + reg
#pragma unroll
    for (int i = 0; i < 4; i++) {
#pragma unroll
        for (int j = 0; j < 4; j++) {
            int n = bn + wn * 64 + j * 16 + rl;
            float bv = bias[n];
#pragma unroll
            for (int r = 0; r < 4; r++) {
                int m = bm + wm * 64 + i * 16 + q * 4 + r;
                float v = acc[i][j][r] + bv;
                if (relu) v = fmaxf(v, 0.f);
                C[(size_t)m * N + n] = f2bf(v);
            }
        }
    }
}

// ---------------------------------------------------------------------------
// Final: out[b] = sigmoid(wide[b] + h2[b] . W3 + b3); one wave per row.
// ---------------------------------------------------------------------------
__global__ __launch_bounds__(256) void final_kernel(
    const uint16_t* __restrict__ h2, const float* __restrict__ W3,
    const float* __restrict__ b3, const float* __restrict__ wide,
    float* __restrict__ out)
{
    int wave = threadIdx.x >> 6, lane = threadIdx.x & 63;
    int row = blockIdx.x * 4 + wave;  // grid 4096
    const uint16_t* hr = h2 + (size_t)row * HDIM + lane * 16;
    u16x8 h0 = *(const u16x8*)hr;
    u16x8 h1 = *(const u16x8*)(hr + 8);
    const float* w3 = W3 + lane * 16;
    float s = 0.f;
#pragma unroll
    for (int t = 0; t < 8; t++) s += bf2f(h0[t]) * w3[t];
#pragma unroll
    for (int t = 0; t < 8; t++) s += bf2f(h1[t]) * w3[8 + t];
#pragma unroll
    for (int off = 32; off; off >>= 1) s += __shfl_down(s, off, 64);
    if (lane == 0) {
        float x = s + wide[row] + b3[0];
        out[row] = 1.f / (1.f + __expf(-x));
    }
}

// ---------------------------------------------------------------------------
extern "C" void kernel_launch(void* const* d_in, const int* in_sizes, int n_in,
                              void* d_out, int out_size, void* d_ws, size_t ws_size,
                              hipStream_t stream) {
    const int*   sp    = (const int*)d_in[0];
    const float* dense = (const float*)d_in[1];
    const float* ww    = (const float*)d_in[2];
    const float* wb    = (const float*)d_in[3];
    const float* emb   = (const float*)d_in[4];
    const float* W1    = (const float*)d_in[5];
    const float* b1    = (const float*)d_in[6];
    const float* W2    = (const float*)d_in[7];
    const float* b2    = (const float*)d_in[8];
    const float* W3    = (const float*)d_in[9];
    const float* b3    = (const float*)d_in[10];
    float* out = (float*)d_out;

    char* ws = (char*)d_ws;
    float*    wide = (float*)ws;                       //     65,536 B
    uint16_t* dxp  = (uint16_t*)(ws + 65536);          //  8,388,608 B
    uint16_t* W1b  = (uint16_t*)(ws + 8454144);        //    524,288 B
    uint16_t* W2b  = (uint16_t*)(ws + 8978432);        //  2,097,152 B
    uint16_t* h1   = (uint16_t*)(ws + 11075584);       // 33,554,432 B
    uint16_t* h2   = (uint16_t*)(ws + 44630016);       // 33,554,432 B -> 78,184,448 total

    prep_kernel<<<2752, 256, 0, stream>>>(sp, dense, emb, W1, W2, ww, wb,
                                          dxp, W1b, W2b, wide);
    gemm_bt<<<(BATCH / 128) * 8, 256, 0, stream>>>(
        dxp, W1b, b1, h1, BATCH, HDIM, KPAD, 1);
    gemm_bt<<<(BATCH / 128) * 8, 256, 0, stream>>>(
        h1, W2b, b2, h2, BATCH, HDIM, HDIM, 1);
    final_kernel<<<BATCH / 4, 256, 0, stream>>>(h2, W3, b3, wide, out);
}

// Round 6
// 191.588 us; speedup vs baseline: 1.4366x; 1.4366x over previous
//
#include <hip/hip_runtime.h>
#include <stdint.h>

// ---------------------------------------------------------------------------
// WideAndDeep: B=16384, F=3, C=256, D=64, H=1024, ND=13
// deep_in = 205 padded to 256.
// GEMM: 256x256 block tile, 1024 threads = 16 waves (4m x 4n) each owning a
// 64x64 output (16 f32x4 = 64 acc regs). BK=32, double-buffered LDS (64 KB),
// global_load_lds(16B) staging, fragment-order LDS. 4x the MFMA work per
// barrier vs the 128x128 tile -> the staging drain hides under compute.
// ---------------------------------------------------------------------------

#define BATCH 16384
#define HDIM 1024
#define KPAD 256
#define DEEP_IN 205

typedef short bf16x8 __attribute__((ext_vector_type(8)));
typedef float f32x4 __attribute__((ext_vector_type(4)));
typedef uint16_t u16x8 __attribute__((ext_vector_type(8)));

__device__ __forceinline__ float bf2f(uint16_t u) {
    uint32_t x = ((uint32_t)u) << 16;
    float f;
    __builtin_memcpy(&f, &x, 4);
    return f;
}

__device__ __forceinline__ uint16_t f2bf(float f) {
    uint32_t x;
    __builtin_memcpy(&x, &f, 4);
    uint32_t r = (x + 0x7fffu + ((x >> 16) & 1u)) >> 16;
    return (uint16_t)r;
}

__device__ __forceinline__ void async_ld16(const uint16_t* g, uint16_t* l) {
    __builtin_amdgcn_global_load_lds(
        (const __attribute__((address_space(1))) uint32_t*)g,
        (__attribute__((address_space(3))) uint32_t*)l, 16, 0, 0);
}

// ---------------------------------------------------------------------------
// Fused prep:
//   blocks [0, 2048)      : build deep_x  [B][256] bf16  (x8 vectorized)
//   blocks [2048, 2560)   : W2 -> bf16               (x8 vectorized)
//   blocks [2560, 2688)   : W1 -> bf16 K-padded      (x8 vectorized)
//   blocks [2688, 2752)   : wide path (fp32 gathers)
// ---------------------------------------------------------------------------
__global__ __launch_bounds__(256) void prep_kernel(
    const int* __restrict__ sp, const float* __restrict__ dense,
    const float* __restrict__ emb,
    const float* __restrict__ W1, const float* __restrict__ W2,
    const float* __restrict__ ww, const float* __restrict__ wb,
    uint16_t* __restrict__ dx, uint16_t* __restrict__ W1b,
    uint16_t* __restrict__ W2b, float* __restrict__ wide)
{
    const int bid = blockIdx.x;
    if (bid < 2048) {                      // ---- deep_x build
        int idx = bid * 256 + threadIdx.x; // < 16384*32
        int b = idx >> 5, c0 = (idx & 31) * 8;
        u16x8 o;
        if (c0 < 192) {
            int f = c0 >> 6, cc = c0 & 63;
            int s = sp[b * 3 + f];
            const float* e = emb + (size_t)(((f << 8) + s) * 64 + cc);
            float4 v0 = *(const float4*)e;
            float4 v1 = *(const float4*)(e + 4);
            o[0] = f2bf(v0.x); o[1] = f2bf(v0.y); o[2] = f2bf(v0.z); o[3] = f2bf(v0.w);
            o[4] = f2bf(v1.x); o[5] = f2bf(v1.y); o[6] = f2bf(v1.z); o[7] = f2bf(v1.w);
        } else {
#pragma unroll
            for (int t = 0; t < 8; t++) {
                int c = c0 + t;
                o[t] = (c >= 192 && c < DEEP_IN) ? f2bf(dense[b * 13 + (c - 192)])
                                                 : (uint16_t)0;
            }
        }
        *(u16x8*)(dx + (size_t)idx * 8) = o;
    } else if (bid < 2560) {               // ---- W2 convert
        int k = (bid - 2048) * 256 + threadIdx.x;  // < 131072
        const float* src = W2 + (size_t)k * 8;
        float4 v0 = *(const float4*)src;
        float4 v1 = *(const float4*)(src + 4);
        u16x8 o;
        o[0] = f2bf(v0.x); o[1] = f2bf(v0.y); o[2] = f2bf(v0.z); o[3] = f2bf(v0.w);
        o[4] = f2bf(v1.x); o[5] = f2bf(v1.y); o[6] = f2bf(v1.z); o[7] = f2bf(v1.w);
        *(u16x8*)(W2b + (size_t)k * 8) = o;
    } else if (bid < 2688) {               // ---- W1 convert, pad 205->256
        int idx = (bid - 2560) * 256 + threadIdx.x;  // < 32768
        int n = idx >> 5, c0 = (idx & 31) * 8;
        u16x8 o;
#pragma unroll
        for (int t = 0; t < 8; t++) {
            int c = c0 + t;
            o[t] = (c < DEEP_IN) ? f2bf(W1[n * DEEP_IN + c]) : (uint16_t)0;
        }
        *(u16x8*)(W1b + (size_t)idx * 8) = o;
    } else {                               // ---- wide path
        int b = (bid - 2688) * 256 + threadIdx.x;  // < 16384
        int s0 = sp[b * 3], s1 = sp[b * 3 + 1], s2 = sp[b * 3 + 2];
        float w = wb[0];
        w += ww[s0] + ww[256 + s1] + ww[512 + s2];
        w += ww[768    + s0 * 3 + s1];
        w += ww[66304  + s0 * 3 + s2];
        w += ww[131840 + s1 * 3 + s2];
        w += ww[197376 + (s0 * 3 + s1) * 3 + s2];
        const float* wd = ww + 16974592;
        float acc = 0.f;
#pragma unroll
        for (int j = 0; j < 13; j++) acc += dense[b * 13 + j] * wd[j];
        wide[b] = w + acc;
    }
}

// ---------------------------------------------------------------------------
// bf16 GEMM: C[M][N] = act(A[M][K] @ Bw[N][K]^T + bias[N])  (all row-major)
// 256x256 tile, 1024 threads = 16 waves (wm = wave>>2, wn = wave&3), each
// wave computes 64x64 (4x4 16x16 frags, 64 acc regs). BK=32 double-buffered.
// Staging: chunk = 16 rows x 32 k = 1 KB; A has 16 chunks, B has 16; wave w
// stages A-chunk w + B-chunk w (2 async_ld16/wave/iter).
// Per iter: 256 MFMA (~1076 cyc) vs ~1300 cyc prefetch -> drain mostly hidden.
// Requires M%256==0, N==1024 (nx=4 hardcoded in swizzle), K%32==0, 16B-align.
// Grid (M/256)*4 = 256 blocks = 1/CU. XCD swizzle: XCD j owns m-bands
// [j*mb8, (j+1)*mb8); its 4 n-sharers of each A-band stay in one L2.
// ---------------------------------------------------------------------------
__global__ __launch_bounds__(1024, 4) void gemm_bt(
    const uint16_t* __restrict__ A, const uint16_t* __restrict__ Bw,
    const float* __restrict__ bias, uint16_t* __restrict__ C,
    int M, int N, int K, int relu)
{
    __shared__ __align__(16) uint16_t Al[2][8192];  // 2 x (256 rows x 32 k)
    __shared__ __align__(16) uint16_t Bl[2][8192];

    const int tid = threadIdx.x;
    const int lane = tid & 63;
    const int wave = tid >> 6;   // 0..15
    const int wm = wave >> 2;    // 0..3 : m-quarter (64 rows)
    const int wn = wave & 3;     // 0..3 : n-quarter (64 cols)

    const int id = blockIdx.x;
    const int xcd = id & 7;
    const int slot = id >> 3;            // 0..31
    const int mb8 = (M >> 8) >> 3;       // m-bands per XCD (8 for M=16384)
    const int by = xcd * mb8 + (slot >> 2);
    const int bx = slot & 3;             // n-band (nx = 4)
    const int bm = by * 256;
    const int bn = bx * 256;
    const int rl = lane & 15, q = lane >> 4;

    f32x4 acc[4][4];
#pragma unroll
    for (int i = 0; i < 4; i++)
#pragma unroll
        for (int j = 0; j < 4; j++) acc[i][j] = (f32x4)0.f;

    // Staging (fragment order): wave w stages A-chunk w and B-chunk w.
    // Lane l lands at chunk_base + l*16B = row l&15, k (l>>4)*8.
    const uint16_t* aS = A + (size_t)(bm + wave * 16 + rl) * K + q * 8;
    const uint16_t* bS = Bw + (size_t)(bn + wave * 16 + rl) * K + q * 8;
    const int dOf = wave * 512;

    // Prologue: tile 0 -> buffer 0
    async_ld16(aS, &Al[0][dOf]);
    async_ld16(bS, &Bl[0][dOf]);
    asm volatile("s_waitcnt vmcnt(0)" ::: "memory");
    __syncthreads();

    int p = 0;
    for (int k0 = 32; k0 < K; k0 += 32) {
        // issue next tile's loads into the other buffer (no wait)
        async_ld16(aS + k0, &Al[p ^ 1][dOf]);
        async_ld16(bS + k0, &Bl[p ^ 1][dOf]);

        // compute current buffer: 16 MFMA
        bf16x8 af[4], bfr[4];
#pragma unroll
        for (int i = 0; i < 4; i++)
            af[i] = *(const bf16x8*)&Al[p][(wm * 4 + i) * 512 + lane * 8];
#pragma unroll
        for (int j = 0; j < 4; j++)
            bfr[j] = *(const bf16x8*)&Bl[p][(wn * 4 + j) * 512 + lane * 8];
#pragma unroll
        for (int i = 0; i < 4; i++)
#pragma unroll
            for (int j = 0; j < 4; j++)
                acc[i][j] = __builtin_amdgcn_mfma_f32_16x16x32_bf16(
                    af[i], bfr[j], acc[i][j], 0, 0, 0);

        asm volatile("s_waitcnt vmcnt(0)" ::: "memory");
        __syncthreads();
        p ^= 1;
    }

    // last tile
    {
        bf16x8 af[4], bfr[4];
#pragma unroll
        for (int i = 0; i < 4; i++)
            af[i] = *(const bf16x8*)&Al[p][(wm * 4 + i) * 512 + lane * 8];
#pragma unroll
        for (int j = 0; j < 4; j++)
            bfr[j] = *(const bf16x8*)&Bl[p][(wn * 4 + j) * 512 + lane * 8];
#pragma unroll
        for (int i = 0; i < 4; i++)
#pragma unroll
            for (int j = 0; j < 4; j++)
                acc[i][j] = __builtin_amdgcn_mfma_f32_16x16x32_bf16(
                    af[i], bfr[j], acc[i][j], 0, 0, 0);
    }

    // Epilogue: C/D layout col = lane&15, row = (lane>>4)*4 + reg
#pragma unroll
    for (int i = 0; i < 4; i++) {
#pragma unroll
        for (int j = 0; j < 4; j++) {
            int n = bn + (wn * 4 + j) * 16 + rl;
            float bv = bias[n];
#pragma unroll
            for (int r = 0; r < 4; r++) {
                int m = bm + (wm * 4 + i) * 16 + q * 4 + r;
                float v = acc[i][j][r] + bv;
                if (relu) v = fmaxf(v, 0.f);
                C[(size_t)m * N + n] = f2bf(v);
            }
        }
    }
}

// ---------------------------------------------------------------------------
// Final: out[b] = sigmoid(wide[b] + h2[b] . W3 + b3); one wave per row.
// ---------------------------------------------------------------------------
__global__ __launch_bounds__(256) void final_kernel(
    const uint16_t* __restrict__ h2, const float* __restrict__ W3,
    const float* __restrict__ b3, const float* __restrict__ wide,
    float* __restrict__ out)
{
    int wave = threadIdx.x >> 6, lane = threadIdx.x & 63;
    int row = blockIdx.x * 4 + wave;  // grid 4096
    const uint16_t* hr = h2 + (size_t)row * HDIM + lane * 16;
    u16x8 h0 = *(const u16x8*)hr;
    u16x8 h1 = *(const u16x8*)(hr + 8);
    const float* w3 = W3 + lane * 16;
    float s = 0.f;
#pragma unroll
    for (int t = 0; t < 8; t++) s += bf2f(h0[t]) * w3[t];
#pragma unroll
    for (int t = 0; t < 8; t++) s += bf2f(h1[t]) * w3[8 + t];
#pragma unroll
    for (int off = 32; off; off >>= 1) s += __shfl_down(s, off, 64);
    if (lane == 0) {
        float x = s + wide[row] + b3[0];
        out[row] = 1.f / (1.f + __expf(-x));
    }
}

// ---------------------------------------------------------------------------
extern "C" void kernel_launch(void* const* d_in, const int* in_sizes, int n_in,
                              void* d_out, int out_size, void* d_ws, size_t ws_size,
                              hipStream_t stream) {
    const int*   sp    = (const int*)d_in[0];
    const float* dense = (const float*)d_in[1];
    const float* ww    = (const float*)d_in[2];
    const float* wb    = (const float*)d_in[3];
    const float* emb   = (const float*)d_in[4];
    const float* W1    = (const float*)d_in[5];
    const float* b1    = (const float*)d_in[6];
    const float* W2    = (const float*)d_in[7];
    const float* b2    = (const float*)d_in[8];
    const float* W3    = (const float*)d_in[9];
    const float* b3    = (const float*)d_in[10];
    float* out = (float*)d_out;

    char* ws = (char*)d_ws;
    float*    wide = (float*)ws;                       //     65,536 B
    uint16_t* dxp  = (uint16_t*)(ws + 65536);          //  8,388,608 B
    uint16_t* W1b  = (uint16_t*)(ws + 8454144);        //    524,288 B
    uint16_t* W2b  = (uint16_t*)(ws + 8978432);        //  2,097,152 B
    uint16_t* h1   = (uint16_t*)(ws + 11075584);       // 33,554,432 B
    uint16_t* h2   = (uint16_t*)(ws + 44630016);       // 33,554,432 B -> 78,184,448 total

    prep_kernel<<<2752, 256, 0, stream>>>(sp, dense, emb, W1, W2, ww, wb,
                                          dxp, W1b, W2b, wide);
    gemm_bt<<<(BATCH / 256) * 4, 1024, 0, stream>>>(
        dxp, W1b, b1, h1, BATCH, HDIM, KPAD, 1);
    gemm_bt<<<(BATCH / 256) * 4, 1024, 0, stream>>>(
        h1, W2b, b2, h2, BATCH, HDIM, HDIM, 1);
    final_kernel<<<BATCH / 4, 256, 0, stream>>>(h2, W3, b3, wide, out);
}

// Round 7
// 184.008 us; speedup vs baseline: 1.4958x; 1.0412x over previous
//
#include <hip/hip_runtime.h>
#include <stdint.h>

// ---------------------------------------------------------------------------
// WideAndDeep: B=16384, F=3, C=256, D=64, H=1024, ND=13
// deep_in = 205 padded to 256.
// GEMM: 128x256 block tile, 512 threads = 8 waves (2m x 4n) each owning 64x64
// (64 acc regs). BK=32 double-buffered LDS (48 KB) -> 2 blocks/CU co-resident
// so one block's barrier drain overlaps the other's MFMA burst (m114).
// GEMM2 fuses the W3 matvec: per-row partials atomicAdd'ed into 'wide',
// h2 never materialized.
// ---------------------------------------------------------------------------

#define BATCH 16384
#define HDIM 1024
#define KPAD 256
#define DEEP_IN 205

typedef short bf16x8 __attribute__((ext_vector_type(8)));
typedef float f32x4 __attribute__((ext_vector_type(4)));
typedef uint16_t u16x8 __attribute__((ext_vector_type(8)));

__device__ __forceinline__ float bf2f(uint16_t u) {
    uint32_t x = ((uint32_t)u) << 16;
    float f;
    __builtin_memcpy(&f, &x, 4);
    return f;
}

__device__ __forceinline__ uint16_t f2bf(float f) {
    uint32_t x;
    __builtin_memcpy(&x, &f, 4);
    uint32_t r = (x + 0x7fffu + ((x >> 16) & 1u)) >> 16;
    return (uint16_t)r;
}

__device__ __forceinline__ void async_ld16(const uint16_t* g, uint16_t* l) {
    __builtin_amdgcn_global_load_lds(
        (const __attribute__((address_space(1))) uint32_t*)g,
        (__attribute__((address_space(3))) uint32_t*)l, 16, 0, 0);
}

// ---------------------------------------------------------------------------
// Fused prep:
//   blocks [0, 2048)      : build deep_x  [B][256] bf16  (x8 vectorized)
//   blocks [2048, 2560)   : W2 -> bf16               (x8 vectorized)
//   blocks [2560, 2688)   : W1 -> bf16 K-padded      (x8 vectorized)
//   blocks [2688, 2752)   : wide path + b3 seed (atomicAdd target for GEMM2)
// ---------------------------------------------------------------------------
__global__ __launch_bounds__(256) void prep_kernel(
    const int* __restrict__ sp, const float* __restrict__ dense,
    const float* __restrict__ emb,
    const float* __restrict__ W1, const float* __restrict__ W2,
    const float* __restrict__ ww, const float* __restrict__ wb,
    const float* __restrict__ b3,
    uint16_t* __restrict__ dx, uint16_t* __restrict__ W1b,
    uint16_t* __restrict__ W2b, float* __restrict__ wide)
{
    const int bid = blockIdx.x;
    if (bid < 2048) {                      // ---- deep_x build
        int idx = bid * 256 + threadIdx.x; // < 16384*32
        int b = idx >> 5, c0 = (idx & 31) * 8;
        u16x8 o;
        if (c0 < 192) {
            int f = c0 >> 6, cc = c0 & 63;
            int s = sp[b * 3 + f];
            const float* e = emb + (size_t)(((f << 8) + s) * 64 + cc);
            float4 v0 = *(const float4*)e;
            float4 v1 = *(const float4*)(e + 4);
            o[0] = f2bf(v0.x); o[1] = f2bf(v0.y); o[2] = f2bf(v0.z); o[3] = f2bf(v0.w);
            o[4] = f2bf(v1.x); o[5] = f2bf(v1.y); o[6] = f2bf(v1.z); o[7] = f2bf(v1.w);
        } else {
#pragma unroll
            for (int t = 0; t < 8; t++) {
                int c = c0 + t;
                o[t] = (c >= 192 && c < DEEP_IN) ? f2bf(dense[b * 13 + (c - 192)])
                                                 : (uint16_t)0;
            }
        }
        *(u16x8*)(dx + (size_t)idx * 8) = o;
    } else if (bid < 2560) {               // ---- W2 convert
        int k = (bid - 2048) * 256 + threadIdx.x;  // < 131072
        const float* src = W2 + (size_t)k * 8;
        float4 v0 = *(const float4*)src;
        float4 v1 = *(const float4*)(src + 4);
        u16x8 o;
        o[0] = f2bf(v0.x); o[1] = f2bf(v0.y); o[2] = f2bf(v0.z); o[3] = f2bf(v0.w);
        o[4] = f2bf(v1.x); o[5] = f2bf(v1.y); o[6] = f2bf(v1.z); o[7] = f2bf(v1.w);
        *(u16x8*)(W2b + (size_t)k * 8) = o;
    } else if (bid < 2688) {               // ---- W1 convert, pad 205->256
        int idx = (bid - 2560) * 256 + threadIdx.x;  // < 32768
        int n = idx >> 5, c0 = (idx & 31) * 8;
        u16x8 o;
#pragma unroll
        for (int t = 0; t < 8; t++) {
            int c = c0 + t;
            o[t] = (c < DEEP_IN) ? f2bf(W1[n * DEEP_IN + c]) : (uint16_t)0;
        }
        *(u16x8*)(W1b + (size_t)idx * 8) = o;
    } else {                               // ---- wide path (+ b3 seed)
        int b = (bid - 2688) * 256 + threadIdx.x;  // < 16384
        int s0 = sp[b * 3], s1 = sp[b * 3 + 1], s2 = sp[b * 3 + 2];
        float w = wb[0] + b3[0];
        w += ww[s0] + ww[256 + s1] + ww[512 + s2];
        w += ww[768    + s0 * 3 + s1];
        w += ww[66304  + s0 * 3 + s2];
        w += ww[131840 + s1 * 3 + s2];
        w += ww[197376 + (s0 * 3 + s1) * 3 + s2];
        const float* wd = ww + 16974592;
        float acc = 0.f;
#pragma unroll
        for (int j = 0; j < 13; j++) acc += dense[b * 13 + j] * wd[j];
        wide[b] = w + acc;
    }
}

// ---------------------------------------------------------------------------
// Shared GEMM core: 128x256 tile, 512 thr = 8 waves (wm=wave>>2 in 0..1,
// wn=wave&3 in 0..3), wave tile 64x64 (4x4 16x16 frags). BK=32 dbuf.
// Staging: A = 8 chunks (wave stages chunk `wave`), B = 16 chunks (wave
// stages 2w, 2w+1). Chunk = 16 rows x 32 k, fragment order, 1 KB.
// Grid (M/128)*4 = 512 blocks = 2/CU. XCD swizzle: XCD j owns m-bands
// [j*16, j*16+16); the 4 n-sharers of each A-band stay in one L2.
// ---------------------------------------------------------------------------
#define GEMM_CORE(A_, B_, K_)                                                  \
    const int tid = threadIdx.x;                                               \
    const int lane = tid & 63;                                                 \
    const int wave = tid >> 6;                                                 \
    const int wm = wave >> 2;                                                  \
    const int wn = wave & 3;                                                   \
    const int id = blockIdx.x;                                                 \
    const int xcd = id & 7;                                                    \
    const int slot = id >> 3;                                                  \
    const int mbX = (M >> 7) >> 3;                                             \
    const int by = xcd * mbX + (slot >> 2);                                    \
    const int bx = slot & 3;                                                   \
    const int bm = by * 128;                                                   \
    const int bn = bx * 256;                                                   \
    const int rl = lane & 15, q = lane >> 4;                                   \
    f32x4 acc[4][4];                                                           \
    _Pragma("unroll") for (int i = 0; i < 4; i++)                              \
        _Pragma("unroll") for (int j = 0; j < 4; j++) acc[i][j] = (f32x4)0.f;  \
    const uint16_t* aS = A_ + (size_t)(bm + wave * 16 + rl) * K_ + q * 8;      \
    const uint16_t* bS0 = B_ + (size_t)(bn + wave * 32 + rl) * K_ + q * 8;     \
    const uint16_t* bS1 = bS0 + (size_t)16 * K_;                               \
    const int dA = wave * 512, dB0 = wave * 1024, dB1 = wave * 1024 + 512;     \
    async_ld16(aS, &Al[0][dA]);                                                \
    async_ld16(bS0, &Bl[0][dB0]);                                              \
    async_ld16(bS1, &Bl[0][dB1]);                                              \
    asm volatile("s_waitcnt vmcnt(0)" ::: "memory");                           \
    __syncthreads();                                                           \
    int p = 0;                                                                 \
    for (int k0 = 32; k0 < K_; k0 += 32) {                                     \
        async_ld16(aS + k0, &Al[p ^ 1][dA]);                                   \
        async_ld16(bS0 + k0, &Bl[p ^ 1][dB0]);                                 \
        async_ld16(bS1 + k0, &Bl[p ^ 1][dB1]);                                 \
        bf16x8 af[4], bfr[4];                                                  \
        _Pragma("unroll") for (int i = 0; i < 4; i++)                          \
            af[i] = *(const bf16x8*)&Al[p][(wm * 4 + i) * 512 + lane * 8];     \
        _Pragma("unroll") for (int j = 0; j < 4; j++)                          \
            bfr[j] = *(const bf16x8*)&Bl[p][(wn * 4 + j) * 512 + lane * 8];    \
        _Pragma("unroll") for (int i = 0; i < 4; i++)                          \
            _Pragma("unroll") for (int j = 0; j < 4; j++)                      \
                acc[i][j] = __builtin_amdgcn_mfma_f32_16x16x32_bf16(           \
                    af[i], bfr[j], acc[i][j], 0, 0, 0);                        \
        asm volatile("s_waitcnt vmcnt(0)" ::: "memory");                       \
        __syncthreads();                                                       \
        p ^= 1;                                                                \
    }                                                                          \
    {                                                                          \
        bf16x8 af[4], bfr[4];                                                  \
        _Pragma("unroll") for (int i = 0; i < 4; i++)                          \
            af[i] = *(const bf16x8*)&Al[p][(wm * 4 + i) * 512 + lane * 8];     \
        _Pragma("unroll") for (int j = 0; j < 4; j++)                          \
            bfr[j] = *(const bf16x8*)&Bl[p][(wn * 4 + j) * 512 + lane * 8];    \
        _Pragma("unroll") for (int i = 0; i < 4; i++)                          \
            _Pragma("unroll") for (int j = 0; j < 4; j++)                      \
                acc[i][j] = __builtin_amdgcn_mfma_f32_16x16x32_bf16(           \
                    af[i], bfr[j], acc[i][j], 0, 0, 0);                        \
    }

// GEMM1: C = relu(A @ Bw^T + bias), written bf16.
__global__ __launch_bounds__(512, 4) void gemm_relu(
    const uint16_t* __restrict__ A, const uint16_t* __restrict__ Bw,
    const float* __restrict__ bias, uint16_t* __restrict__ C,
    int M, int N, int K)
{
    __shared__ __align__(16) uint16_t Al[2][4096];   // 128 x 32
    __shared__ __align__(16) uint16_t Bl[2][8192];   // 256 x 32
    GEMM_CORE(A, Bw, K)
#pragma unroll
    for (int i = 0; i < 4; i++) {
#pragma unroll
        for (int j = 0; j < 4; j++) {
            int n = bn + (wn * 4 + j) * 16 + rl;
            float bv = bias[n];
#pragma unroll
            for (int r = 0; r < 4; r++) {
                int m = bm + (wm * 4 + i) * 16 + q * 4 + r;
                float v = fmaxf(acc[i][j][r] + bv, 0.f);
                C[(size_t)m * N + n] = f2bf(v);
            }
        }
    }
}

// GEMM2 fused: per-row partial of relu(acc + b2) . W3, atomicAdd into outacc.
__global__ __launch_bounds__(512, 4) void gemm_fused(
    const uint16_t* __restrict__ A, const uint16_t* __restrict__ Bw,
    const float* __restrict__ bias, const float* __restrict__ W3,
    float* __restrict__ outacc, int M, int N, int K)
{
    __shared__ __align__(16) uint16_t Al[2][4096];
    __shared__ __align__(16) uint16_t Bl[2][8192];
    GEMM_CORE(A, Bw, K)
    float bv[4], w3v[4];
#pragma unroll
    for (int j = 0; j < 4; j++) {
        int n = bn + (wn * 4 + j) * 16 + rl;
        bv[j] = bias[n];
        w3v[j] = W3[n];
    }
#pragma unroll
    for (int i = 0; i < 4; i++) {
#pragma unroll
        for (int r = 0; r < 4; r++) {
            float pt = 0.f;
#pragma unroll
            for (int j = 0; j < 4; j++)
                pt += fmaxf(acc[i][j][r] + bv[j], 0.f) * w3v[j];
            // reduce over the 16 rl-lanes of this q-group
            pt += __shfl_xor(pt, 1);
            pt += __shfl_xor(pt, 2);
            pt += __shfl_xor(pt, 4);
            pt += __shfl_xor(pt, 8);
            if (rl == 0) {
                int m = bm + (wm * 4 + i) * 16 + q * 4 + r;
                atomicAdd(&outacc[m], pt);
            }
        }
    }
}

// ---------------------------------------------------------------------------
// Sigmoid over the accumulated logits. Grid 64 x 256.
// ---------------------------------------------------------------------------
__global__ __launch_bounds__(256) void sigmoid_kernel(
    const float* __restrict__ outacc, float* __restrict__ out)
{
    int b = blockIdx.x * 256 + threadIdx.x;
    out[b] = 1.f / (1.f + __expf(-outacc[b]));
}

// ---------------------------------------------------------------------------
extern "C" void kernel_launch(void* const* d_in, const int* in_sizes, int n_in,
                              void* d_out, int out_size, void* d_ws, size_t ws_size,
                              hipStream_t stream) {
    const int*   sp    = (const int*)d_in[0];
    const float* dense = (const float*)d_in[1];
    const float* ww    = (const float*)d_in[2];
    const float* wb    = (const float*)d_in[3];
    const float* emb   = (const float*)d_in[4];
    const float* W1    = (const float*)d_in[5];
    const float* b1    = (const float*)d_in[6];
    const float* W2    = (const float*)d_in[7];
    const float* b2    = (const float*)d_in[8];
    const float* W3    = (const float*)d_in[9];
    const float* b3    = (const float*)d_in[10];
    float* out = (float*)d_out;

    char* ws = (char*)d_ws;
    float*    wide = (float*)ws;                       //     65,536 B
    uint16_t* dxp  = (uint16_t*)(ws + 65536);          //  8,388,608 B
    uint16_t* W1b  = (uint16_t*)(ws + 8454144);        //    524,288 B
    uint16_t* W2b  = (uint16_t*)(ws + 8978432);        //  2,097,152 B
    uint16_t* h1   = (uint16_t*)(ws + 11075584);       // 33,554,432 B -> 44,630,016 total

    prep_kernel<<<2752, 256, 0, stream>>>(sp, dense, emb, W1, W2, ww, wb, b3,
                                          dxp, W1b, W2b, wide);
    gemm_relu<<<(BATCH / 128) * 4, 512, 0, stream>>>(
        dxp, W1b, b1, h1, BATCH, HDIM, KPAD);
    gemm_fused<<<(BATCH / 128) * 4, 512, 0, stream>>>(
        h1, W2b, b2, W3, wide, BATCH, HDIM, HDIM);
    sigmoid_kernel<<<BATCH / 256, 256, 0, stream>>>(wide, out);
}